// Round 1
// baseline (473.767 us; speedup 1.0000x reference)
//
#include <hip/hip_runtime.h>

// Generalized Lotka-Volterra, RK4, D=64 coupled components, 2048 independent
// batch elements, 255 sequential steps, trajectory out (batch, 256, 64) fp32.
//
// Mapping: one 64-lane wave per batch element; lane i owns state component i
// and row i of the interaction matrix A (64 VGPRs). Per RK4 stage, the stage
// state is broadcast through a wave-private LDS buffer (uniform-address
// ds_read_b128 -> hardware broadcast, conflict-free). Wave-synchronous: no
// __syncthreads needed, just lgkmcnt drain (DS pipe is in-order per wave).

constexpr int D   = 64;   // state dimension == wavefront size
constexpr int NT  = 256;  // trajectory length (255 RK4 steps)
constexpr int WPB = 4;    // waves (= batch elements) per block

__global__ __launch_bounds__(WPB * 64, 2)
void glv_rk4_kernel(const float* __restrict__ x0,
                    const float* __restrict__ r,
                    const float* __restrict__ A,
                    const float* __restrict__ tgrid,
                    float* __restrict__ out)
{
    const int lane = threadIdx.x & 63;
    const int wid  = threadIdx.x >> 6;
    const int b    = blockIdx.x * WPB + wid;   // batch element for this wave

    __shared__ float xs[WPB][2][D];            // per-wave stage-state buffers

    // Row i of A into registers (one-time; A is 16 KB, L2-resident).
    float a[D];
#pragma unroll
    for (int j = 0; j < D; j += 4) {
        const float4 v = *reinterpret_cast<const float4*>(A + lane * D + j);
        a[j + 0] = v.x; a[j + 1] = v.y; a[j + 2] = v.z; a[j + 3] = v.w;
    }

    const float ri = r[lane];
    const float dt = tgrid[1] - tgrid[0];
    const float h2 = 0.5f * dt;
    const float h6 = dt * (1.0f / 6.0f);

    float x = x0[(size_t)b * D + lane];

    float* const buf0 = &xs[wid][0][0];
    float* const buf1 = &xs[wid][1][0];

    // f(xt) = xt * (r + A @ xt), evaluated wave-cooperatively.
    auto feval = [&](float xt, float* buf) -> float {
        buf[lane] = xt;                                   // ds_write_b32
        asm volatile("s_waitcnt lgkmcnt(0)" ::: "memory"); // wave-sync LDS
        float acc0 = 0.f, acc1 = 0.f, acc2 = 0.f, acc3 = 0.f;
#pragma unroll
        for (int j = 0; j < D; j += 16) {
            const float4 v0 = *reinterpret_cast<const float4*>(buf + j);
            const float4 v1 = *reinterpret_cast<const float4*>(buf + j + 4);
            const float4 v2 = *reinterpret_cast<const float4*>(buf + j + 8);
            const float4 v3 = *reinterpret_cast<const float4*>(buf + j + 12);
            acc0 = fmaf(a[j +  0], v0.x, acc0);
            acc1 = fmaf(a[j +  1], v0.y, acc1);
            acc2 = fmaf(a[j +  2], v0.z, acc2);
            acc3 = fmaf(a[j +  3], v0.w, acc3);
            acc0 = fmaf(a[j +  4], v1.x, acc0);
            acc1 = fmaf(a[j +  5], v1.y, acc1);
            acc2 = fmaf(a[j +  6], v1.z, acc2);
            acc3 = fmaf(a[j +  7], v1.w, acc3);
            acc0 = fmaf(a[j +  8], v2.x, acc0);
            acc1 = fmaf(a[j +  9], v2.y, acc1);
            acc2 = fmaf(a[j + 10], v2.z, acc2);
            acc3 = fmaf(a[j + 11], v2.w, acc3);
            acc0 = fmaf(a[j + 12], v3.x, acc0);
            acc1 = fmaf(a[j + 13], v3.y, acc1);
            acc2 = fmaf(a[j + 14], v3.z, acc2);
            acc3 = fmaf(a[j + 15], v3.w, acc3);
        }
        return xt * (ri + ((acc0 + acc1) + (acc2 + acc3)));
    };

    float* o = out + (size_t)b * NT * D + lane;
    *o = x; o += D;                                       // t = 0 is x0

    for (int t = 1; t < NT; ++t) {
        const float k1 = feval(x, buf0);
        const float k2 = feval(fmaf(h2, k1, x), buf1);
        const float k3 = feval(fmaf(h2, k2, x), buf0);
        const float k4 = feval(fmaf(dt, k3, x), buf1);
        x = fmaf(h6, (k1 + k4) + 2.0f * (k2 + k3), x);
        *o = x; o += D;                                   // coalesced 256 B/wave
    }
}

extern "C" void kernel_launch(void* const* d_in, const int* in_sizes, int n_in,
                              void* d_out, int out_size, void* d_ws, size_t ws_size,
                              hipStream_t stream) {
    const float* x0    = (const float*)d_in[0];
    const float* r     = (const float*)d_in[1];
    const float* A     = (const float*)d_in[2];
    const float* tgrid = (const float*)d_in[3];
    float* out         = (float*)d_out;

    const int batch = in_sizes[0] / D;          // 2048
    dim3 grid(batch / WPB);                     // 512 blocks
    dim3 block(WPB * 64);                       // 256 threads = 4 waves

    glv_rk4_kernel<<<grid, block, 0, stream>>>(x0, r, A, tgrid, out);
}

// Round 2
// 388.448 us; speedup vs baseline: 1.2196x; 1.2196x over previous
//
#include <hip/hip_runtime.h>

// Generalized Lotka-Volterra, RK4, D=64, batch 2048, 255 steps,
// trajectory out (batch, 256, 64) fp32.
//
// Mapping: one 64-lane wave per batch element; lane i owns state component i
// and row i of A in 64 VGPRs (fully constant-indexed -> SROA-promoted).
// Broadcast of stage-state component x_j to all lanes is done with
// v_readlane_b32 (compile-time lane index) -> SGPR, consumed directly by
// v_fma_f32's single allowed SGPR operand. No LDS, no waitcnt, no wave sync:
// the per-stage cross-lane broadcast has zero memory-latency cost.

constexpr int D   = 64;   // state dimension == wavefront size
constexpr int NT  = 256;  // trajectory length (255 RK4 steps)
constexpr int WPB = 4;    // waves (= batch elements) per block

__device__ __forceinline__ float bcast(float v, int srclane) {
    return __uint_as_float(__builtin_amdgcn_readlane(__float_as_uint(v), srclane));
}

__global__ __launch_bounds__(WPB * 64)
void glv_rk4_kernel(const float* __restrict__ x0,
                    const float* __restrict__ r,
                    const float* __restrict__ A,
                    const float* __restrict__ tgrid,
                    float* __restrict__ out)
{
    const int lane = threadIdx.x & 63;
    const int wid  = threadIdx.x >> 6;
    const int b    = blockIdx.x * WPB + wid;   // batch element for this wave

    // Row `lane` of A into registers (one-time; A is 16 KB, L2-resident).
    float a[D];
#pragma unroll
    for (int j = 0; j < D; j += 4) {
        const float4 v = *reinterpret_cast<const float4*>(A + lane * D + j);
        a[j + 0] = v.x; a[j + 1] = v.y; a[j + 2] = v.z; a[j + 3] = v.w;
    }

    const float ri = r[lane];
    const float dt = tgrid[1] - tgrid[0];
    const float h2 = 0.5f * dt;
    const float h6 = dt * (1.0f / 6.0f);

    float x = x0[(size_t)b * D + lane];

    // f(xt) = xt * (r + A @ xt): readlane-broadcast matvec, no LDS.
#define FEVAL(XT, RES)                                                        \
    do {                                                                      \
        const float xt_ = (XT);                                               \
        float acc0 = ri, acc1 = 0.f, acc2 = 0.f, acc3 = 0.f;                  \
        _Pragma("unroll")                                                     \
        for (int j = 0; j < D; j += 4) {                                      \
            acc0 = fmaf(a[j + 0], bcast(xt_, j + 0), acc0);                   \
            acc1 = fmaf(a[j + 1], bcast(xt_, j + 1), acc1);                   \
            acc2 = fmaf(a[j + 2], bcast(xt_, j + 2), acc2);                   \
            acc3 = fmaf(a[j + 3], bcast(xt_, j + 3), acc3);                   \
        }                                                                     \
        RES = xt_ * ((acc0 + acc1) + (acc2 + acc3));                          \
    } while (0)

    float* o = out + (size_t)b * NT * D + lane;
    *o = x; o += D;                                       // t = 0 is x0

    for (int t = 1; t < NT; ++t) {
        float k1, k2, k3, k4;
        FEVAL(x, k1);
        FEVAL(fmaf(h2, k1, x), k2);
        FEVAL(fmaf(h2, k2, x), k3);
        FEVAL(fmaf(dt, k3, x), k4);
        x = fmaf(h6, (k1 + k4) + 2.0f * (k2 + k3), x);
        *o = x; o += D;                                   // coalesced 256 B/wave
    }
#undef FEVAL
}

extern "C" void kernel_launch(void* const* d_in, const int* in_sizes, int n_in,
                              void* d_out, int out_size, void* d_ws, size_t ws_size,
                              hipStream_t stream) {
    const float* x0    = (const float*)d_in[0];
    const float* r     = (const float*)d_in[1];
    const float* A     = (const float*)d_in[2];
    const float* tgrid = (const float*)d_in[3];
    float* out         = (float*)d_out;

    const int batch = in_sizes[0] / D;          // 2048
    dim3 grid(batch / WPB);                     // 512 blocks
    dim3 block(WPB * 64);                       // 256 threads = 4 waves

    glv_rk4_kernel<<<grid, block, 0, stream>>>(x0, r, A, tgrid, out);
}